// Round 1
// baseline (6011.374 us; speedup 1.0000x reference)
//
#include <hip/hip_runtime.h>
#include <math.h>

// ---- problem constants ----
static constexpr int Bc   = 4;
static constexpr int Sc   = 512;
static constexpr int Dc   = 512;     // d_model
static constexpr int Hc   = 8;
static constexpr int DKc  = 64;
static constexpr int NXc  = 6;
static constexpr int DFFc = 2048;
static constexpr int Vc   = 37000;
static constexpr int Mc   = Bc * Sc; // 2048 rows
static constexpr float BN_EPS = 1e-5f;

#define NEG_INF (-1e30f)

// ---------------- elementwise ----------------
__global__ void embed_k(const int* __restrict__ idx, const float* __restrict__ emb,
                        float* __restrict__ x) {
  int i = blockIdx.x * blockDim.x + threadIdx.x;
  if (i >= Mc * Dc) return;
  int r = i >> 9;          // / 512
  int d = i & 511;
  x[i] = emb[(long)idx[r] * Dc + d] * 8.0f;   // * sqrt(d_k)=8
}

__global__ void add_k(float* __restrict__ x, const float* __restrict__ y, int n) {
  int i = blockIdx.x * blockDim.x + threadIdx.x;
  if (i < n) x[i] += y[i];
}

// O[b,h,s,e] -> cc[b*S+s, h*64+e]
__global__ void concat_k(const float* __restrict__ O, float* __restrict__ out) {
  int i = blockIdx.x * blockDim.x + threadIdx.x;
  if (i >= Mc * Dc) return;
  int r = i >> 9, c = i & 511;
  int b = r >> 9, s = r & 511;
  int h = c >> 6, e = c & 63;
  out[i] = O[((((long)b * Hc + h) * Sc + s) << 6) + e];
}

// ---------------- GEMM NN: C = alpha*A@B (+bias)(+relu) ----------------
// 64x64 tile, BK=16, 16x16 threads, 4x4 per thread.
// mode==0: A += z*aB, B += z*bB.  mode==1 (per-head proj): A += (z/H)*aB, B += (z%H)*bB.
__global__ __launch_bounds__(256) void gemm_nn(
    const float* __restrict__ A, const float* __restrict__ Bm,
    const float* __restrict__ bias, float* __restrict__ C,
    int M, int N, int K, long aB, long bB, long cB, int mode,
    float alpha, int relu)
{
  int z = blockIdx.z;
  if (mode) { A += (long)(z / Hc) * aB; Bm += (long)(z % Hc) * bB; }
  else      { A += (long)z * aB;        Bm += (long)z * bB; }
  C += (long)z * cB;

  __shared__ float sA[16][68];
  __shared__ float sB[16][68];
  int tx = threadIdx.x, ty = threadIdx.y;
  int tid = ty * 16 + tx;
  int row0 = blockIdx.x * 64, col0 = blockIdx.y * 64;
  int am = tid >> 2, ak = (tid & 3) << 2;   // A: 64 rows x 16 k
  int bk = tid >> 4, bc = (tid & 15) << 2;  // B: 16 k x 64 cols
  float acc[4][4] = {{0.f}};

  for (int k0 = 0; k0 < K; k0 += 16) {
    float4 av = *(const float4*)(A + (long)(row0 + am) * K + k0 + ak);
    float4 bv = make_float4(0.f, 0.f, 0.f, 0.f);
    if (col0 + bc < N) bv = *(const float4*)(Bm + (long)(k0 + bk) * N + col0 + bc);
    __syncthreads();
    sA[ak + 0][am] = av.x; sA[ak + 1][am] = av.y;
    sA[ak + 2][am] = av.z; sA[ak + 3][am] = av.w;
    *(float4*)&sB[bk][bc] = bv;
    __syncthreads();
#pragma unroll
    for (int kk = 0; kk < 16; kk++) {
      float4 a = *(const float4*)&sA[kk][ty << 2];
      float4 b = *(const float4*)&sB[kk][tx << 2];
      acc[0][0] += a.x * b.x; acc[0][1] += a.x * b.y; acc[0][2] += a.x * b.z; acc[0][3] += a.x * b.w;
      acc[1][0] += a.y * b.x; acc[1][1] += a.y * b.y; acc[1][2] += a.y * b.z; acc[1][3] += a.y * b.w;
      acc[2][0] += a.z * b.x; acc[2][1] += a.z * b.y; acc[2][2] += a.z * b.z; acc[2][3] += a.z * b.w;
      acc[3][0] += a.w * b.x; acc[3][1] += a.w * b.y; acc[3][2] += a.w * b.z; acc[3][3] += a.w * b.w;
    }
  }

  int c = col0 + (tx << 2);
  if (c < N) {
    float bx = 0.f, by = 0.f, bz = 0.f, bw = 0.f;
    if (bias) { bx = bias[c]; by = bias[c + 1]; bz = bias[c + 2]; bw = bias[c + 3]; }
#pragma unroll
    for (int i2 = 0; i2 < 4; i2++) {
      int r = row0 + (ty << 2) + i2;
      float4 o;
      o.x = acc[i2][0] * alpha + bx;
      o.y = acc[i2][1] * alpha + by;
      o.z = acc[i2][2] * alpha + bz;
      o.w = acc[i2][3] * alpha + bw;
      if (relu) {
        o.x = fmaxf(o.x, 0.f); o.y = fmaxf(o.y, 0.f);
        o.z = fmaxf(o.z, 0.f); o.w = fmaxf(o.w, 0.f);
      }
      *(float4*)(C + (long)r * N + c) = o;
    }
  }
}

// ---------------- GEMM NT: C = alpha * A @ B^T (batched) ----------------
// A [M,K], B [N,K] row-major; used for scores = Q K^T / 8  (K=64).
__global__ __launch_bounds__(256) void gemm_nt(
    const float* __restrict__ A, const float* __restrict__ Bm, float* __restrict__ C,
    int M, int N, int K, long aB, long bB, long cB, float alpha)
{
  int z = blockIdx.z;
  A += (long)z * aB; Bm += (long)z * bB; C += (long)z * cB;

  __shared__ float sA[16][68];
  __shared__ float sB[16][68];
  int tx = threadIdx.x, ty = threadIdx.y;
  int tid = ty * 16 + tx;
  int row0 = blockIdx.x * 64, col0 = blockIdx.y * 64;
  int am = tid >> 2, ak = (tid & 3) << 2;
  float acc[4][4] = {{0.f}};

  for (int k0 = 0; k0 < K; k0 += 16) {
    float4 av = *(const float4*)(A  + (long)(row0 + am) * K + k0 + ak);
    float4 bv = *(const float4*)(Bm + (long)(col0 + am) * K + k0 + ak);
    __syncthreads();
    sA[ak + 0][am] = av.x; sA[ak + 1][am] = av.y;
    sA[ak + 2][am] = av.z; sA[ak + 3][am] = av.w;
    sB[ak + 0][am] = bv.x; sB[ak + 1][am] = bv.y;
    sB[ak + 2][am] = bv.z; sB[ak + 3][am] = bv.w;
    __syncthreads();
#pragma unroll
    for (int kk = 0; kk < 16; kk++) {
      float4 a = *(const float4*)&sA[kk][ty << 2];
      float4 b = *(const float4*)&sB[kk][tx << 2];
      acc[0][0] += a.x * b.x; acc[0][1] += a.x * b.y; acc[0][2] += a.x * b.z; acc[0][3] += a.x * b.w;
      acc[1][0] += a.y * b.x; acc[1][1] += a.y * b.y; acc[1][2] += a.y * b.z; acc[1][3] += a.y * b.w;
      acc[2][0] += a.z * b.x; acc[2][1] += a.z * b.y; acc[2][2] += a.z * b.z; acc[2][3] += a.z * b.w;
      acc[3][0] += a.w * b.x; acc[3][1] += a.w * b.y; acc[3][2] += a.w * b.z; acc[3][3] += a.w * b.w;
    }
  }
#pragma unroll
  for (int i2 = 0; i2 < 4; i2++) {
    int r = row0 + (ty << 2) + i2;
    int c = col0 + (tx << 2);
    float4 o;
    o.x = acc[i2][0] * alpha; o.y = acc[i2][1] * alpha;
    o.z = acc[i2][2] * alpha; o.w = acc[i2][3] * alpha;
    *(float4*)(C + (long)r * N + c) = o;
  }
}

// ---------------- attention softmax (row of 512, causal mask optional) ----
__global__ __launch_bounds__(256) void attn_softmax(float* __restrict__ sc, int causal) {
  int row = blockIdx.x;                 // (b*H+h)*S + s
  int s = row & (Sc - 1);
  float* p = sc + (long)row * Sc;
  int t0 = threadIdx.x, t1 = threadIdx.x + 256;
  int limit = causal ? (s + 1) : Sc;

  float v0 = (t0 < limit) ? p[t0] : NEG_INF;
  float v1 = (t1 < limit) ? p[t1] : NEG_INF;
  float mx = fmaxf(v0, v1);
  __shared__ float sm[4], sm2[4];
#pragma unroll
  for (int o = 32; o > 0; o >>= 1) mx = fmaxf(mx, __shfl_down(mx, o, 64));
  if ((threadIdx.x & 63) == 0) sm[threadIdx.x >> 6] = mx;
  __syncthreads();
  mx = fmaxf(fmaxf(sm[0], sm[1]), fmaxf(sm[2], sm[3]));

  float e0 = (t0 < limit) ? __expf(v0 - mx) : 0.f;
  float e1 = (t1 < limit) ? __expf(v1 - mx) : 0.f;
  float sum = e0 + e1;
#pragma unroll
  for (int o = 32; o > 0; o >>= 1) sum += __shfl_down(sum, o, 64);
  if ((threadIdx.x & 63) == 0) sm2[threadIdx.x >> 6] = sum;
  __syncthreads();
  sum = sm2[0] + sm2[1] + sm2[2] + sm2[3];
  float inv = 1.f / sum;
  p[t0] = e0 * inv;
  p[t1] = e1 * inv;
}

// ---------------- BatchNorm (training-mode, biased var over B*S) ----------
__global__ __launch_bounds__(256) void bn_stats(const float* __restrict__ x,
    const float* __restrict__ g, const float* __restrict__ b,
    float* __restrict__ scale, float* __restrict__ shift)
{
  int c = blockIdx.x;                 // channel
  float s = 0.f, s2 = 0.f;
  for (int r = threadIdx.x; r < Mc; r += 256) {
    float v = x[(long)r * Dc + c];
    s += v; s2 += v * v;
  }
  __shared__ float ssm[4], ssm2[4];
#pragma unroll
  for (int o = 32; o > 0; o >>= 1) { s += __shfl_down(s, o, 64); s2 += __shfl_down(s2, o, 64); }
  if ((threadIdx.x & 63) == 0) { ssm[threadIdx.x >> 6] = s; ssm2[threadIdx.x >> 6] = s2; }
  __syncthreads();
  if (threadIdx.x == 0) {
    s  = ssm[0] + ssm[1] + ssm[2] + ssm[3];
    s2 = ssm2[0] + ssm2[1] + ssm2[2] + ssm2[3];
    float mu  = s * (1.f / Mc);
    float var = s2 * (1.f / Mc) - mu * mu;
    float sc = g[c] * rsqrtf(var + BN_EPS);
    scale[c] = sc;
    shift[c] = b[c] - mu * sc;
  }
}

__global__ void bn_apply(float* __restrict__ x, const float* __restrict__ scale,
                         const float* __restrict__ shift) {
  int i = blockIdx.x * blockDim.x + threadIdx.x;
  if (i >= Mc * Dc) return;
  int c = i & 511;
  x[i] = x[i] * scale[c] + shift[c];
}

// ---------------- vocab softmax: 37000 cols, register-resident ------------
static constexpr int VT = 37;  // ceil(37000/1024)
__global__ __launch_bounds__(1024) void vocab_softmax(float* __restrict__ out) {
  long row = blockIdx.x;
  float* p = out + row * (long)Vc;
  float v[VT];
  float mx = NEG_INF;
#pragma unroll
  for (int j = 0; j < VT; j++) {
    int c = threadIdx.x + j * 1024;
    v[j] = (c < Vc) ? p[c] : NEG_INF;
    mx = fmaxf(mx, v[j]);
  }
  __shared__ float sm[16], sm2[16];
#pragma unroll
  for (int o = 32; o > 0; o >>= 1) mx = fmaxf(mx, __shfl_down(mx, o, 64));
  if ((threadIdx.x & 63) == 0) sm[threadIdx.x >> 6] = mx;
  __syncthreads();
  float m2 = sm[0];
#pragma unroll
  for (int i = 1; i < 16; i++) m2 = fmaxf(m2, sm[i]);
  mx = m2;

  float sum = 0.f;
#pragma unroll
  for (int j = 0; j < VT; j++) {
    int c = threadIdx.x + j * 1024;
    float e = (c < Vc) ? __expf(v[j] - mx) : 0.f;
    v[j] = e; sum += e;
  }
#pragma unroll
  for (int o = 32; o > 0; o >>= 1) sum += __shfl_down(sum, o, 64);
  if ((threadIdx.x & 63) == 0) sm2[threadIdx.x >> 6] = sum;
  __syncthreads();
  float s2 = 0.f;
#pragma unroll
  for (int i = 0; i < 16; i++) s2 += sm2[i];
  float inv = 1.f / s2;
#pragma unroll
  for (int j = 0; j < VT; j++) {
    int c = threadIdx.x + j * 1024;
    if (c < Vc) p[c] = v[j] * inv;
  }
}

// ---------------- orchestration ----------------
extern "C" void kernel_launch(void* const* d_in, const int* in_sizes, int n_in,
                              void* d_out, int out_size, void* d_ws, size_t ws_size,
                              hipStream_t stream) {
  const int*   idx   = (const int*)d_in[0];
  const float* enc   = (const float*)d_in[1];
  const float* emb   = (const float*)d_in[2];
  const float* Wq1   = (const float*)d_in[3];
  const float* Wk1   = (const float*)d_in[4];
  const float* Wv1   = (const float*)d_in[5];
  const float* Wo1   = (const float*)d_in[6];
  const float* Wq2   = (const float*)d_in[7];
  const float* Wk2   = (const float*)d_in[8];
  const float* Wv2   = (const float*)d_in[9];
  const float* Wo2   = (const float*)d_in[10];
  const float* gamma = (const float*)d_in[11];
  const float* beta  = (const float*)d_in[12];
  const float* W1    = (const float*)d_in[13];
  const float* b1    = (const float*)d_in[14];
  const float* W2    = (const float*)d_in[15];
  const float* b2    = (const float*)d_in[16];
  const float* Wout  = (const float*)d_in[17];
  const float* bout  = (const float*)d_in[18];
  float* out = (float*)d_out;

  // workspace layout (floats) — total ~19.9M floats ~= 80 MB
  float* ws = (float*)d_ws;
  const long MD = (long)Mc * Dc;                 // 1,048,576
  float* x      = ws;
  float* t0     = x  + MD;
  float* Q      = t0 + MD;
  float* Kb     = Q  + MD;
  float* Vb     = Kb + MD;
  float* Ob     = Vb + MD;
  float* cc     = Ob + MD;
  float* ff1    = cc + MD;                       // 2048*2048
  float* scores = ff1 + (long)Mc * DFFc;         // 4*8*512*512
  float* scalep = scores + (long)Bc * Hc * Sc * Sc;
  float* shiftp = scalep + Dc;

  dim3 blk(16, 16);
  const int n1 = Mc * Dc;
  const int eb = (n1 + 255) / 256;
  const long sSD  = (long)Sc * Dc;   // x batch stride (per b)
  const long sDK  = (long)Dc * DKc;  // weight per-head stride
  const long sSK  = (long)Sc * DKc;  // Q/K/V per-(b,h) stride
  const long sSS  = (long)Sc * Sc;   // scores per-(b,h) stride

  embed_k<<<eb, 256, 0, stream>>>(idx, emb, x);

  for (int l = 0; l < NXc; l++) {
    // ======== self-attention (causal) ========
    {
      const float* wq = Wq1 + (long)l * Hc * Dc * DKc;
      const float* wk = Wk1 + (long)l * Hc * Dc * DKc;
      const float* wv = Wv1 + (long)l * Hc * Dc * DKc;
      const float* wo = Wo1 + (long)l * Dc * Dc;
      dim3 gp(Sc / 64, 1, Bc * Hc);
      gemm_nn<<<gp, blk, 0, stream>>>(x, wq, nullptr, Q,  Sc, DKc, Dc, sSD, sDK, sSK, 1, 1.f, 0);
      gemm_nn<<<gp, blk, 0, stream>>>(x, wk, nullptr, Kb, Sc, DKc, Dc, sSD, sDK, sSK, 1, 1.f, 0);
      gemm_nn<<<gp, blk, 0, stream>>>(x, wv, nullptr, Vb, Sc, DKc, Dc, sSD, sDK, sSK, 1, 1.f, 0);
      dim3 gs(Sc / 64, Sc / 64, Bc * Hc);
      gemm_nt<<<gs, blk, 0, stream>>>(Q, Kb, scores, Sc, Sc, DKc, sSK, sSK, sSS, 0.125f);
      attn_softmax<<<Bc * Hc * Sc, 256, 0, stream>>>(scores, 1);
      dim3 go(Sc / 64, 1, Bc * Hc);
      gemm_nn<<<go, blk, 0, stream>>>(scores, Vb, nullptr, Ob, Sc, DKc, Sc, sSS, sSK, sSK, 0, 1.f, 0);
      concat_k<<<eb, 256, 0, stream>>>(Ob, cc);
      dim3 gw(Mc / 64, Dc / 64, 1);
      gemm_nn<<<gw, blk, 0, stream>>>(cc, wo, nullptr, t0, Mc, Dc, Dc, 0, 0, 0, 0, 1.f, 0);
      add_k<<<eb, 256, 0, stream>>>(x, t0, n1);
      bn_stats<<<Dc, 256, 0, stream>>>(x, gamma + (long)(l * 3 + 0) * Dc, beta + (long)(l * 3 + 0) * Dc, scalep, shiftp);
      bn_apply<<<eb, 256, 0, stream>>>(x, scalep, shiftp);
    }
    // ======== cross-attention ========
    {
      const float* wq = Wq2 + (long)l * Hc * Dc * DKc;
      const float* wk = Wk2 + (long)l * Hc * Dc * DKc;
      const float* wv = Wv2 + (long)l * Hc * Dc * DKc;
      const float* wo = Wo2 + (long)l * Dc * Dc;
      dim3 gp(Sc / 64, 1, Bc * Hc);
      gemm_nn<<<gp, blk, 0, stream>>>(x,   wq, nullptr, Q,  Sc, DKc, Dc, sSD, sDK, sSK, 1, 1.f, 0);
      gemm_nn<<<gp, blk, 0, stream>>>(enc, wk, nullptr, Kb, Sc, DKc, Dc, sSD, sDK, sSK, 1, 1.f, 0);
      gemm_nn<<<gp, blk, 0, stream>>>(enc, wv, nullptr, Vb, Sc, DKc, Dc, sSD, sDK, sSK, 1, 1.f, 0);
      dim3 gs(Sc / 64, Sc / 64, Bc * Hc);
      gemm_nt<<<gs, blk, 0, stream>>>(Q, Kb, scores, Sc, Sc, DKc, sSK, sSK, sSS, 0.125f);
      attn_softmax<<<Bc * Hc * Sc, 256, 0, stream>>>(scores, 0);
      dim3 go(Sc / 64, 1, Bc * Hc);
      gemm_nn<<<go, blk, 0, stream>>>(scores, Vb, nullptr, Ob, Sc, DKc, Sc, sSS, sSK, sSK, 0, 1.f, 0);
      concat_k<<<eb, 256, 0, stream>>>(Ob, cc);
      dim3 gw(Mc / 64, Dc / 64, 1);
      gemm_nn<<<gw, blk, 0, stream>>>(cc, wo, nullptr, t0, Mc, Dc, Dc, 0, 0, 0, 0, 1.f, 0);
      add_k<<<eb, 256, 0, stream>>>(x, t0, n1);
      bn_stats<<<Dc, 256, 0, stream>>>(x, gamma + (long)(l * 3 + 1) * Dc, beta + (long)(l * 3 + 1) * Dc, scalep, shiftp);
      bn_apply<<<eb, 256, 0, stream>>>(x, scalep, shiftp);
    }
    // ======== FFN ========
    {
      dim3 g1(Mc / 64, DFFc / 64, 1);
      gemm_nn<<<g1, blk, 0, stream>>>(x, W1 + (long)l * Dc * DFFc, b1 + (long)l * DFFc, ff1,
                                      Mc, DFFc, Dc, 0, 0, 0, 0, 1.f, 1);
      dim3 g2(Mc / 64, Dc / 64, 1);
      gemm_nn<<<g2, blk, 0, stream>>>(ff1, W2 + (long)l * DFFc * Dc, b2 + (long)l * Dc, t0,
                                      Mc, Dc, DFFc, 0, 0, 0, 0, 1.f, 0);
      add_k<<<eb, 256, 0, stream>>>(x, t0, n1);
      bn_stats<<<Dc, 256, 0, stream>>>(x, gamma + (long)(l * 3 + 2) * Dc, beta + (long)(l * 3 + 2) * Dc, scalep, shiftp);
      bn_apply<<<eb, 256, 0, stream>>>(x, scalep, shiftp);
    }
  }

  // ======== final projection + vocab softmax ========
  dim3 gf(Mc / 64, (Vc + 63) / 64, 1);
  gemm_nn<<<gf, blk, 0, stream>>>(x, Wout, bout, out, Mc, Vc, Dc, 0, 0, 0, 0, 1.f, 0);
  vocab_softmax<<<Mc, 1024, 0, stream>>>(out);
}